// Round 1
// baseline (623.081 us; speedup 1.0000x reference)
//
#include <hip/hip_runtime.h>

typedef __attribute__((ext_vector_type(8))) short short8;
typedef __attribute__((ext_vector_type(4))) float f32x4;

__device__ __forceinline__ unsigned short f32_to_bf16(float f) {
    unsigned int u = __float_as_uint(f);
    u += 0x7FFFu + ((u >> 16) & 1u);   // round-to-nearest-even
    return (unsigned short)(u >> 16);
}

__device__ __forceinline__ short8 load8_f32_as_bf16(const float* __restrict__ ap) {
    f32x4 f0 = *(const f32x4*)ap;
    f32x4 f1 = *(const f32x4*)(ap + 4);
    union { short8 s; unsigned short u[8]; } cv;
#pragma unroll
    for (int t = 0; t < 4; ++t) {
        cv.u[t]     = f32_to_bf16(f0[t]);
        cv.u[t + 4] = f32_to_bf16(f1[t]);
    }
    return cv.s;
}

// ---------------------------------------------------------------------------
// Uniform NT GEMM: C[M,N] = A[M,K] * B[N,K]^T   (bf16 inputs, fp32 accum)
// AMODE: 0 = A bf16; 1 = A fp32 (convert in staging); 2 = split: k<1024 from
//        A (bf16, lda), k>=1024 from A2 (fp32, lda2) -- the concat trick.
// EPI:   0 = store bf16; 1 = *scale, store fp32; 2 = relu(+bias), bf16;
//        3 = +bias, fp32.
// CAUSAL: skip blocks entirely above the diagonal (scores GEMM).
// KLIMIT: kend = min(K, m0+64)  (PV GEMM: P[i][k]==0 for k>i).
// ---------------------------------------------------------------------------
constexpr int LDSW = 40;   // 64+pad shorts; 80B row stride -> 2-way bank alias (free)

template<int AMODE, int EPI, bool CAUSAL, bool KLIMIT>
__global__ __launch_bounds__(256, 2)
void gemm_nt(const unsigned short* __restrict__ A, const float* __restrict__ A2,
             int lda, int lda2,
             const unsigned short* __restrict__ B, int ldb,
             void* __restrict__ C, int ldc, int K,
             const float* __restrict__ bias, float scale)
{
    int m0 = blockIdx.y * 64;
    int n0 = blockIdx.x * 64;
    if (CAUSAL && n0 >= m0 + 64) return;   // uniform early exit, before any barrier

    __shared__ __align__(16) short As[64 * LDSW];
    __shared__ __align__(16) short Bs[64 * LDSW];

    int tid  = threadIdx.x;
    int lane = tid & 63, wid = tid >> 6;
    int wm = (wid & 1) * 32, wn = (wid >> 1) * 32;
    int srow = tid >> 2, sc8 = (tid & 3) * 8;   // staging: 64 rows x 32 k, 16B/thread
    int fr = lane & 15, fq = lane >> 4;          // fragment row / quad

    int kend = KLIMIT ? min(K, m0 + 64) : K;

    f32x4 acc00 = {0.f,0.f,0.f,0.f}, acc01 = {0.f,0.f,0.f,0.f};
    f32x4 acc10 = {0.f,0.f,0.f,0.f}, acc11 = {0.f,0.f,0.f,0.f};

    for (int k0 = 0; k0 < kend; k0 += 32) {
        int gk = k0 + sc8;
        short8 av;
        if (AMODE == 0) {
            av = *(const short8*)(A + (size_t)(m0 + srow) * lda + gk);
        } else if (AMODE == 1) {
            av = load8_f32_as_bf16(A2 + (size_t)(m0 + srow) * lda2 + gk);
        } else {
            if (gk < 1024)   // k0 multiple of 32 -> branch uniform per k-step
                av = *(const short8*)(A + (size_t)(m0 + srow) * lda + gk);
            else
                av = load8_f32_as_bf16(A2 + (size_t)(m0 + srow) * lda2 + (gk - 1024));
        }
        *(short8*)(&As[srow * LDSW + sc8]) = av;
        short8 bv = *(const short8*)(B + (size_t)(n0 + srow) * ldb + gk);
        *(short8*)(&Bs[srow * LDSW + sc8]) = bv;
        __syncthreads();

        short8 a0  = *(const short8*)(&As[(wm      + fr) * LDSW + fq * 8]);
        short8 a1  = *(const short8*)(&As[(wm + 16 + fr) * LDSW + fq * 8]);
        short8 b0  = *(const short8*)(&Bs[(wn      + fr) * LDSW + fq * 8]);
        short8 b1v = *(const short8*)(&Bs[(wn + 16 + fr) * LDSW + fq * 8]);

        acc00 = __builtin_amdgcn_mfma_f32_16x16x32_bf16(a0, b0,  acc00, 0, 0, 0);
        acc01 = __builtin_amdgcn_mfma_f32_16x16x32_bf16(a0, b1v, acc01, 0, 0, 0);
        acc10 = __builtin_amdgcn_mfma_f32_16x16x32_bf16(a1, b0,  acc10, 0, 0, 0);
        acc11 = __builtin_amdgcn_mfma_f32_16x16x32_bf16(a1, b1v, acc11, 0, 0, 0);
        __syncthreads();
    }

    // epilogue: C/D layout col = lane&15, row = (lane>>4)*4 + reg  [m89/m91]
    f32x4 accs[2][2] = {{acc00, acc01}, {acc10, acc11}};
#pragma unroll
    for (int i = 0; i < 2; ++i)
#pragma unroll
    for (int j = 0; j < 2; ++j)
#pragma unroll
    for (int r = 0; r < 4; ++r) {
        int row = m0 + wm + i * 16 + fq * 4 + r;
        int col = n0 + wn + j * 16 + fr;
        float v = accs[i][j][r];
        if (EPI == 0) {
            ((unsigned short*)C)[(size_t)row * ldc + col] = f32_to_bf16(v);
        } else if (EPI == 1) {
            ((float*)C)[(size_t)row * ldc + col] = v * scale;
        } else if (EPI == 2) {
            v += bias[col];
            v = v > 0.f ? v : 0.f;
            ((unsigned short*)C)[(size_t)row * ldc + col] = f32_to_bf16(v);
        } else {
            ((float*)C)[(size_t)row * ldc + col] = v + bias[col];
        }
    }
}

// ---------------------------------------------------------------------------
// fp32 [rows,cols] -> bf16 [cols,rows] transpose (weights, once per call)
// ---------------------------------------------------------------------------
__global__ __launch_bounds__(256)
void transpose_f32_bf16(const float* __restrict__ in, unsigned short* __restrict__ out,
                        int rows, int cols)
{
    __shared__ float t[32][33];
    int tx = threadIdx.x, ty = threadIdx.y;
    int r0 = blockIdx.y * 32, c0 = blockIdx.x * 32;
    for (int i = ty; i < 32; i += 8)
        t[i][tx] = in[(size_t)(r0 + i) * cols + c0 + tx];
    __syncthreads();
    for (int i = ty; i < 32; i += 8)
        out[(size_t)(c0 + i) * rows + r0 + tx] = f32_to_bf16(t[tx][i]);
}

// v (bf16, inside qkv, ld 3072) -> vT [4][1024][2048]
__global__ __launch_bounds__(256)
void transpose_v_kernel(const unsigned short* __restrict__ qkv, unsigned short* __restrict__ vT)
{
    int b = blockIdx.z;
    const unsigned short* in = qkv + (size_t)b * 2048 * 3072 + 2048;
    unsigned short* out = vT + (size_t)b * 1024 * 2048;
    __shared__ unsigned short t[32][33];
    int tx = threadIdx.x, ty = threadIdx.y;
    int r0 = blockIdx.y * 32, c0 = blockIdx.x * 32;  // r over 2048 keys, c over 1024 dims
    for (int i = ty; i < 32; i += 8)
        t[i][tx] = in[(size_t)(r0 + i) * 3072 + c0 + tx];
    __syncthreads();
    for (int i = ty; i < 32; i += 8)
        out[(size_t)(c0 + i) * 2048 + r0 + tx] = t[tx][i];
}

// ---------------------------------------------------------------------------
// causal row softmax: S fp32 [2048,2048] (lower triangle valid) -> P bf16,
// zeros above diagonal so PV can run a dense (K-limited) GEMM.
// ---------------------------------------------------------------------------
__global__ __launch_bounds__(256)
void softmax_causal(float* __restrict__ S, unsigned short* __restrict__ P)
{
    int row = blockIdx.x;
    int tid = threadIdx.x;
    int lane = tid & 63, w = tid >> 6;
    int n = row + 1;
    float* srow = S + (size_t)row * 2048;
    unsigned short* prow = P + (size_t)row * 2048;
    __shared__ float red[4];

    float m = -1e30f;
    for (int j = tid; j < n; j += 256) m = fmaxf(m, srow[j]);
#pragma unroll
    for (int o = 32; o > 0; o >>= 1) m = fmaxf(m, __shfl_down(m, o));
    if (lane == 0) red[w] = m;
    __syncthreads();
    m = fmaxf(fmaxf(red[0], red[1]), fmaxf(red[2], red[3]));
    __syncthreads();

    float s = 0.f;
    for (int j = tid; j < n; j += 256) {
        float e = __expf(srow[j] - m);
        srow[j] = e;
        s += e;
    }
#pragma unroll
    for (int o = 32; o > 0; o >>= 1) s += __shfl_down(s, o);
    if (lane == 0) red[w] = s;
    __syncthreads();
    s = red[0] + red[1] + red[2] + red[3];
    float inv = 1.f / s;

    for (int j = tid; j < 2048; j += 256) {
        float v = (j < n) ? srow[j] * inv : 0.f;
        prow[j] = f32_to_bf16(v);
    }
}

// ---------------------------------------------------------------------------
extern "C" void kernel_launch(void* const* d_in, const int* in_sizes, int n_in,
                              void* d_out, int out_size, void* d_ws, size_t ws_size,
                              hipStream_t stream)
{
    const float* x  = (const float*)d_in[0];   // [8192,1024]
    const float* Wq = (const float*)d_in[1];   // [1024,1024]
    const float* Wk = (const float*)d_in[2];
    const float* Wv = (const float*)d_in[3];
    const float* W1 = (const float*)d_in[4];   // [2048,1024]
    const float* b1 = (const float*)d_in[5];   // [1024]
    const float* W2 = (const float*)d_in[6];   // [1024,1024]
    const float* b2 = (const float*)d_in[7];   // [1024]
    float* out = (float*)d_out;                // [8192,1024] fp32

    char* p = (char*)d_ws;
    auto alloc = [&](size_t bytes) { char* r = p; p += bytes; return r; };
    unsigned short* WT   = (unsigned short*)alloc((size_t)3072 * 1024 * 2); // [Wq;Wk;Wv]^T
    unsigned short* W1T  = (unsigned short*)alloc((size_t)1024 * 2048 * 2);
    unsigned short* W2T  = (unsigned short*)alloc((size_t)1024 * 1024 * 2);
    unsigned short* qkv  = (unsigned short*)alloc((size_t)8192 * 3072 * 2); // [s][q|k|v]
    unsigned short* vT   = (unsigned short*)alloc((size_t)4 * 1024 * 2048 * 2);
    float*          S    = (float*)         alloc((size_t)2048 * 2048 * 4); // per-batch, reused
    unsigned short* P    = (unsigned short*)alloc((size_t)2048 * 2048 * 2); // per-batch, reused
    unsigned short* attn = (unsigned short*)alloc((size_t)8192 * 1024 * 2);
    unsigned short* h1   = (unsigned short*)alloc((size_t)8192 * 1024 * 2);
    // total ~139 MB

    dim3 tb(32, 8);
    transpose_f32_bf16<<<dim3(32, 32), tb, 0, stream>>>(Wq, WT,               1024, 1024);
    transpose_f32_bf16<<<dim3(32, 32), tb, 0, stream>>>(Wk, WT + 1024 * 1024, 1024, 1024);
    transpose_f32_bf16<<<dim3(32, 32), tb, 0, stream>>>(Wv, WT + 2048 * 1024, 1024, 1024);
    transpose_f32_bf16<<<dim3(32, 64), tb, 0, stream>>>(W1, W1T, 2048, 1024);
    transpose_f32_bf16<<<dim3(32, 32), tb, 0, stream>>>(W2, W2T, 1024, 1024);

    // QKV: qkv[8192,3072] = bf16(x) @ WT^T   (A converted fp32->bf16 in staging)
    gemm_nt<1, 0, false, false><<<dim3(3072 / 64, 8192 / 64), 256, 0, stream>>>(
        nullptr, x, 0, 1024, WT, 1024, qkv, 3072, 1024, nullptr, 0.f);

    transpose_v_kernel<<<dim3(1024 / 32, 2048 / 32, 4), tb, 0, stream>>>(qkv, vT);

    for (int b = 0; b < 4; ++b) {
        const unsigned short* qb = qkv + (size_t)b * 2048 * 3072;
        const unsigned short* kb = qb + 1024;
        // S = (q @ k^T) * 1/32, causal block skip; fp32 out
        gemm_nt<0, 1, true, false><<<dim3(32, 32), 256, 0, stream>>>(
            qb, nullptr, 3072, 0, kb, 3072, S, 2048, 1024, nullptr, 0.03125f);
        softmax_causal<<<2048, 256, 0, stream>>>(S, P);
        // attn_b = P @ v   (K limited to the diagonal block)
        gemm_nt<0, 0, false, true><<<dim3(1024 / 64, 2048 / 64), 256, 0, stream>>>(
            P, nullptr, 2048, 0, vT + (size_t)b * 1024 * 2048, 2048,
            attn + (size_t)b * 2048 * 1024, 1024, 2048, nullptr, 0.f);
    }

    // MLP1: h1 = relu([attn | x] @ W1 + b1)  -- concat via split-A, no materialization
    gemm_nt<2, 2, false, false><<<dim3(1024 / 64, 8192 / 64), 256, 0, stream>>>(
        attn, x, 1024, 1024, W1T, 2048, h1, 1024, 2048, b1, 0.f);
    // MLP2: out = h1 @ W2 + b2  (fp32 to d_out)
    gemm_nt<0, 3, false, false><<<dim3(1024 / 64, 8192 / 64), 256, 0, stream>>>(
        h1, nullptr, 1024, 0, W2T, 1024, out, 1024, 1024, b2, 0.f);
}

// Round 2
// 400.682 us; speedup vs baseline: 1.5551x; 1.5551x over previous
//
#include <hip/hip_runtime.h>
#include <stdint.h>

typedef __attribute__((ext_vector_type(8))) short short8;
typedef __attribute__((ext_vector_type(4))) float f32x4;

__device__ __forceinline__ unsigned short f32_to_bf16(float f) {
    unsigned int u = __float_as_uint(f);
    u += 0x7FFFu + ((u >> 16) & 1u);   // round-to-nearest-even
    return (unsigned short)(u >> 16);
}

__device__ __forceinline__ short8 load8_f32_as_bf16(const float* __restrict__ ap) {
    f32x4 f0 = *(const f32x4*)ap;
    f32x4 f1 = *(const f32x4*)(ap + 4);
    union { short8 s; unsigned short u[8]; } cv;
#pragma unroll
    for (int t = 0; t < 4; ++t) {
        cv.u[t]     = f32_to_bf16(f0[t]);
        cv.u[t + 4] = f32_to_bf16(f1[t]);
    }
    return cv.s;
}

// async global->LDS DMA, 16B per lane. LDS dest = wave-uniform base + lane*16
// (m104/m108), so pass the per-lane pointer computed in lane order.
__device__ __forceinline__ void gld_lds16(const void* g, void* l) {
    __builtin_amdgcn_global_load_lds(
        (const __attribute__((address_space(1))) unsigned int*)(unsigned long long)(uintptr_t)g,
        (__attribute__((address_space(3))) unsigned int*)(unsigned int)(uintptr_t)l,
        16, 0, 0);
}

// ---------------------------------------------------------------------------
// m97-style NT GEMM: C[M,N] = A[M,K] * B[N,K]^T, bf16 in, fp32 accum.
// 128x128 tile, BK=32, 256 thr = 4 waves in 2x2, 64x64/wave via 4x4 16x16x32.
// Staging: global_load_lds width=16; XOR swizzle chunk c' = c ^ (r&3) applied
// on the GLOBAL source so LDS reads are 2-way-conflict max (free, m136).
// AMODE: 0 = A only; 2 = split-K source: k<ksplit from A, k>=ksplit from A2
//        (both bf16) -- the concat trick for MLP1.
// EPI: 0 bf16; 1 fp32*scale; 2 relu(+bias) bf16; 3 +bias fp32.
// CAUSAL: skip blocks with n0 >= m0+128 (scores). KLIMIT: kend=min(K,m0+128) (PV).
// ---------------------------------------------------------------------------
template<int AMODE, int EPI, bool CAUSAL, bool KLIMIT>
__global__ __launch_bounds__(256, 2)
void gemm128(const unsigned short* __restrict__ A, const unsigned short* __restrict__ A2,
             int lda, int lda2, int ksplit,
             const unsigned short* __restrict__ B, int ldb,
             void* __restrict__ C, int ldc, int K,
             long aStride, long bStride, long cStride,   // per-z strides (elements)
             const float* __restrict__ bias, float scale)
{
    int m0 = blockIdx.y * 128;
    int n0 = blockIdx.x * 128;
    if (CAUSAL && n0 >= m0 + 128) return;   // uniform early exit, before any barrier

    int z = blockIdx.z;
    const unsigned short* Ab = A + (size_t)z * aStride;
    const unsigned short* Bb = B + (size_t)z * bStride;

    __shared__ __align__(16) short As[128 * 32];
    __shared__ __align__(16) short Bs[128 * 32];

    int tid  = threadIdx.x;
    int lane = tid & 63, wid = tid >> 6;
    int wm = (wid & 1) * 64, wn = (wid >> 1) * 64;
    int fr = lane & 15, fq = lane >> 4;
    int swz = (fq ^ (fr & 3)) * 16;          // lane-constant read swizzle (bytes)

    // staging: thread handles 16B chunks q=tid and q=tid+256 of each 8KB tile
    int r0 = tid >> 2,          c0 = (tid & 3) ^ (r0 & 3);          // global chunk
    int r1 = (tid + 256) >> 2,  c1 = (tid & 3) ^ (r1 & 3);
    char* AsB = (char*)As;  char* BsB = (char*)Bs;
    void* dA0 = AsB + tid * 16;          void* dA1 = AsB + (tid + 256) * 16;
    void* dB0 = BsB + tid * 16;          void* dB1 = BsB + (tid + 256) * 16;

    int kend = KLIMIT ? min(K, m0 + 128) : K;

    f32x4 acc[4][4];
#pragma unroll
    for (int i = 0; i < 4; ++i)
#pragma unroll
    for (int j = 0; j < 4; ++j) acc[i][j] = f32x4{0.f, 0.f, 0.f, 0.f};

    for (int k0 = 0; k0 < kend; k0 += 32) {
        const unsigned short* Asrc = Ab;
        int koff = k0, ldax = lda;
        if (AMODE == 2 && k0 >= ksplit) { Asrc = A2; koff = k0 - ksplit; ldax = lda2; }

        gld_lds16(Asrc + (size_t)(m0 + r0) * ldax + koff + c0 * 8, dA0);
        gld_lds16(Asrc + (size_t)(m0 + r1) * ldax + koff + c1 * 8, dA1);
        gld_lds16(Bb   + (size_t)(n0 + r0) * ldb  + k0   + c0 * 8, dB0);
        gld_lds16(Bb   + (size_t)(n0 + r1) * ldb  + k0   + c1 * 8, dB1);
        __syncthreads();   // drains vmcnt before barrier -> LDS data visible

        short8 a[4], b[4];
#pragma unroll
        for (int i = 0; i < 4; ++i) {
            a[i] = *(const short8*)(AsB + (wm + i * 16 + fr) * 64 + swz);
            b[i] = *(const short8*)(BsB + (wn + i * 16 + fr) * 64 + swz);
        }
#pragma unroll
        for (int i = 0; i < 4; ++i)
#pragma unroll
        for (int j = 0; j < 4; ++j)
            acc[i][j] = __builtin_amdgcn_mfma_f32_16x16x32_bf16(a[i], b[j], acc[i][j], 0, 0, 0);
        __syncthreads();   // all ds_reads done before next tile's DMA overwrites
    }

    // epilogue: C/D layout col = lane&15, row = (lane>>4)*4 + reg  [m89/m91]
#pragma unroll
    for (int i = 0; i < 4; ++i)
#pragma unroll
    for (int j = 0; j < 4; ++j)
#pragma unroll
    for (int r = 0; r < 4; ++r) {
        int row = m0 + wm + i * 16 + fq * 4 + r;
        int col = n0 + wn + j * 16 + fr;
        float v = acc[i][j][r];
        if (EPI == 0) {
            ((unsigned short*)C + (size_t)z * cStride)[(size_t)row * ldc + col] = f32_to_bf16(v);
        } else if (EPI == 1) {
            ((float*)C + (size_t)z * cStride)[(size_t)row * ldc + col] = v * scale;
        } else if (EPI == 2) {
            v += bias[col];
            v = v > 0.f ? v : 0.f;
            ((unsigned short*)C + (size_t)z * cStride)[(size_t)row * ldc + col] = f32_to_bf16(v);
        } else {
            ((float*)C + (size_t)z * cStride)[(size_t)row * ldc + col] = v + bias[col];
        }
    }
}

// ---------------------------------------------------------------------------
__global__ __launch_bounds__(256)
void f32_to_bf16_vec(const float* __restrict__ in, unsigned short* __restrict__ out)
{
    size_t i = ((size_t)blockIdx.x * 256 + threadIdx.x) * 8;
    *(short8*)(out + i) = load8_f32_as_bf16(in + i);
}

// fp32 [rows,cols] -> bf16 [cols,rows] transpose (weights, once per call)
__global__ __launch_bounds__(256)
void transpose_f32_bf16(const float* __restrict__ in, unsigned short* __restrict__ out,
                        int rows, int cols)
{
    __shared__ float t[32][33];
    int tx = threadIdx.x, ty = threadIdx.y;
    int r0 = blockIdx.y * 32, c0 = blockIdx.x * 32;
    for (int i = ty; i < 32; i += 8)
        t[i][tx] = in[(size_t)(r0 + i) * cols + c0 + tx];
    __syncthreads();
    for (int i = ty; i < 32; i += 8)
        out[(size_t)(c0 + i) * rows + r0 + tx] = f32_to_bf16(t[tx][i]);
}

// v (bf16, inside qkv, ld 3072) -> vT [4][1024][2048]
__global__ __launch_bounds__(256)
void transpose_v_kernel(const unsigned short* __restrict__ qkv, unsigned short* __restrict__ vT)
{
    int b = blockIdx.z;
    const unsigned short* in = qkv + (size_t)b * 2048 * 3072 + 2048;
    unsigned short* out = vT + (size_t)b * 1024 * 2048;
    __shared__ unsigned short t[32][33];
    int tx = threadIdx.x, ty = threadIdx.y;
    int r0 = blockIdx.y * 32, c0 = blockIdx.x * 32;
    for (int i = ty; i < 32; i += 8)
        t[i][tx] = in[(size_t)(r0 + i) * 3072 + c0 + tx];
    __syncthreads();
    for (int i = ty; i < 32; i += 8)
        out[(size_t)(c0 + i) * 2048 + r0 + tx] = t[tx][i];
}

// causal row softmax: S fp32 (lower triangle valid) -> P bf16 w/ zero upper
__global__ __launch_bounds__(256)
void softmax_causal(float* __restrict__ S, unsigned short* __restrict__ P,
                    long sStride, long pStride)
{
    int row = blockIdx.x;
    int z = blockIdx.y;
    int tid = threadIdx.x;
    int lane = tid & 63, w = tid >> 6;
    int n = row + 1;
    float* srow = S + (size_t)z * sStride + (size_t)row * 2048;
    unsigned short* prow = P + (size_t)z * pStride + (size_t)row * 2048;
    __shared__ float red[4];

    float m = -1e30f;
    for (int j = tid; j < n; j += 256) m = fmaxf(m, srow[j]);
#pragma unroll
    for (int o = 32; o > 0; o >>= 1) m = fmaxf(m, __shfl_down(m, o));
    if (lane == 0) red[w] = m;
    __syncthreads();
    m = fmaxf(fmaxf(red[0], red[1]), fmaxf(red[2], red[3]));
    __syncthreads();

    float s = 0.f;
    for (int j = tid; j < n; j += 256) {
        float e = __expf(srow[j] - m);
        srow[j] = e;
        s += e;
    }
#pragma unroll
    for (int o = 32; o > 0; o >>= 1) s += __shfl_down(s, o);
    if (lane == 0) red[w] = s;
    __syncthreads();
    s = red[0] + red[1] + red[2] + red[3];
    float inv = 1.f / s;

    for (int j = tid; j < 2048; j += 256) {
        float v = (j < n) ? srow[j] * inv : 0.f;
        prow[j] = f32_to_bf16(v);
    }
}

// ---------------------------------------------------------------------------
extern "C" void kernel_launch(void* const* d_in, const int* in_sizes, int n_in,
                              void* d_out, int out_size, void* d_ws, size_t ws_size,
                              hipStream_t stream)
{
    const float* x  = (const float*)d_in[0];   // [8192,1024]
    const float* Wq = (const float*)d_in[1];
    const float* Wk = (const float*)d_in[2];
    const float* Wv = (const float*)d_in[3];
    const float* W1 = (const float*)d_in[4];   // [2048,1024]
    const float* b1 = (const float*)d_in[5];
    const float* W2 = (const float*)d_in[6];   // [1024,1024]
    const float* b2 = (const float*)d_in[7];
    float* out = (float*)d_out;                // [8192,1024] fp32

    size_t off = 0;
    auto alloc = [&](size_t bytes) {
        char* r = (char*)d_ws + off;
        off += (bytes + 255) & ~(size_t)255;
        return r;
    };
    unsigned short* WT   = (unsigned short*)alloc((size_t)3072 * 1024 * 2);
    unsigned short* W1T  = (unsigned short*)alloc((size_t)1024 * 2048 * 2);
    unsigned short* W2T  = (unsigned short*)alloc((size_t)1024 * 1024 * 2);
    unsigned short* xb   = (unsigned short*)alloc((size_t)8192 * 1024 * 2);
    unsigned short* qkv  = (unsigned short*)alloc((size_t)8192 * 3072 * 2);
    unsigned short* vT   = (unsigned short*)alloc((size_t)4 * 1024 * 2048 * 2);
    unsigned short* attn = (unsigned short*)alloc((size_t)8192 * 1024 * 2);
    size_t fixed = off;

    // batched path needs S fp32 [4,2048,2048] + P bf16 [4,2048,2048]
    size_t needBatched = fixed + (size_t)4 * 2048 * 2048 * 4 + (size_t)4 * 2048 * 2048 * 2 + 512;
    int NZ = (ws_size >= needBatched) ? 4 : 1;

    float*          S = (float*)         alloc((size_t)NZ * 2048 * 2048 * 4);
    unsigned short* P = (unsigned short*)alloc((size_t)NZ * 2048 * 2048 * 2);
    unsigned short* h1 = (unsigned short*)S;   // S dead after softmax; MLP1 output aliases it

    dim3 tb(32, 8);
    transpose_f32_bf16<<<dim3(32, 32), tb, 0, stream>>>(Wq, WT,               1024, 1024);
    transpose_f32_bf16<<<dim3(32, 32), tb, 0, stream>>>(Wk, WT + 1024 * 1024, 1024, 1024);
    transpose_f32_bf16<<<dim3(32, 32), tb, 0, stream>>>(Wv, WT + 2048 * 1024, 1024, 1024);
    transpose_f32_bf16<<<dim3(32, 64), tb, 0, stream>>>(W1, W1T, 2048, 1024);
    transpose_f32_bf16<<<dim3(32, 32), tb, 0, stream>>>(W2, W2T, 1024, 1024);
    f32_to_bf16_vec<<<4096, 256, 0, stream>>>(x, xb);

    // QKV: qkv[8192,3072] = xb @ WT^T
    gemm128<0, 0, false, false><<<dim3(24, 64, 1), 256, 0, stream>>>(
        xb, nullptr, 1024, 0, 0, WT, 1024, qkv, 3072, 1024, 0, 0, 0, nullptr, 0.f);

    transpose_v_kernel<<<dim3(32, 64, 4), tb, 0, stream>>>(qkv, vT);

    for (int b = 0; b < 4; b += NZ) {
        const unsigned short* qb = qkv + (size_t)b * 2048 * 3072;
        // S = (q @ k^T) * 1/32, causal block skip
        gemm128<0, 1, true, false><<<dim3(16, 16, NZ), 256, 0, stream>>>(
            qb, nullptr, 3072, 0, 0, qb + 1024, 3072, S, 2048, 1024,
            (long)2048 * 3072, (long)2048 * 3072, (long)2048 * 2048, nullptr, 0.03125f);
        softmax_causal<<<dim3(2048, NZ), 256, 0, stream>>>(
            S, P, (long)2048 * 2048, (long)2048 * 2048);
        // attn = P @ v  (K limited to diagonal block)
        gemm128<0, 0, false, true><<<dim3(8, 16, NZ), 256, 0, stream>>>(
            P, nullptr, 2048, 0, 0, vT + (size_t)b * 1024 * 2048, 2048,
            attn + (size_t)b * 2048 * 1024, 1024, 2048,
            (long)2048 * 2048, (long)1024 * 2048, (long)2048 * 1024, nullptr, 0.f);
    }

    // MLP1: h1 = relu([attn | x] @ W1 + b1), split-A concat trick
    gemm128<2, 2, false, false><<<dim3(8, 64, 1), 256, 0, stream>>>(
        attn, xb, 1024, 1024, 1024, W1T, 2048, h1, 1024, 2048, 0, 0, 0, b1, 0.f);
    // MLP2: out = h1 @ W2 + b2 (fp32 to d_out)
    gemm128<0, 3, false, false><<<dim3(8, 64, 1), 256, 0, stream>>>(
        h1, nullptr, 1024, 0, 0, W2T, 1024, out, 1024, 1024, 0, 0, 0, b2, 0.f);
}

// Round 3
// 382.554 us; speedup vs baseline: 1.6287x; 1.0474x over previous
//
#include <hip/hip_runtime.h>
#include <stdint.h>

typedef __attribute__((ext_vector_type(8))) short short8;
typedef __attribute__((ext_vector_type(4))) float f32x4;

__device__ __forceinline__ unsigned short f32_to_bf16(float f) {
    unsigned int u = __float_as_uint(f);
    u += 0x7FFFu + ((u >> 16) & 1u);   // round-to-nearest-even
    return (unsigned short)(u >> 16);
}
__device__ __forceinline__ float bf16_to_f32(unsigned short h) {
    return __uint_as_float((unsigned int)h << 16);
}

__device__ __forceinline__ short8 load8_f32_as_bf16(const float* __restrict__ ap) {
    f32x4 f0 = *(const f32x4*)ap;
    f32x4 f1 = *(const f32x4*)(ap + 4);
    union { short8 s; unsigned short u[8]; } cv;
#pragma unroll
    for (int t = 0; t < 4; ++t) {
        cv.u[t]     = f32_to_bf16(f0[t]);
        cv.u[t + 4] = f32_to_bf16(f1[t]);
    }
    return cv.s;
}

// async global->LDS DMA, 16B/lane; LDS dest = wave-uniform base + lane*16 (m104/m108)
__device__ __forceinline__ void gld_lds16(const void* g, void* l) {
    __builtin_amdgcn_global_load_lds(
        (const __attribute__((address_space(1))) unsigned int*)(unsigned long long)(uintptr_t)g,
        (__attribute__((address_space(3))) unsigned int*)(unsigned int)(uintptr_t)l,
        16, 0, 0);
}

// ---------------------------------------------------------------------------
// m97-style NT GEMM: C[M,N] = A[M,K]*B[N,K]^T, bf16 in, fp32 accum.
// 128x128 tile, BK=32, 4 waves 2x2, 4x4 16x16x32 MFMA per wave.
// LDS swizzle: chunk' = c ^ ((row>>2)&3)  -> same-bank pairs are (fr,fr+2)
// only = 2-way alias = free (m136). (R1's c^(row&3) left lanes {0,4,8,12}
// 4-way-conflicted: bank = 16*(fr&1)+4*chunk' was constant over fr&3==const.)
// AMODE: 0 = A only; 2 = split at ksplit: A then A2 (concat trick for MLP1).
// EPI: 0 bf16 | 2 relu(+bias[col]) bf16 | 3 +bias[col] fp32
//      4 *bias[z*biasStride+row] bf16 (PV invl) | 5 *scale bf16 (scores)
// CAUSAL: skip blocks n0 >= m0+128. KLIMIT: kend = min(K, m0+128).
// ---------------------------------------------------------------------------
template<int AMODE, int EPI, bool CAUSAL, bool KLIMIT>
__global__ __launch_bounds__(256, 2)
void gemm128(const unsigned short* __restrict__ A, const unsigned short* __restrict__ A2,
             int lda, int lda2, int ksplit,
             const unsigned short* __restrict__ B, int ldb,
             void* __restrict__ C, int ldc, int K,
             long aStride, long bStride, long cStride,
             const float* __restrict__ bias, long biasStride, float scale)
{
    int m0 = blockIdx.y * 128;
    int n0 = blockIdx.x * 128;
    if (CAUSAL && n0 >= m0 + 128) return;   // uniform early exit, before any barrier

    int z = blockIdx.z;
    const unsigned short* Ab = A + (size_t)z * aStride;
    const unsigned short* Bb = B + (size_t)z * bStride;

    __shared__ __align__(16) short As[128 * 32];
    __shared__ __align__(16) short Bs[128 * 32];

    int tid  = threadIdx.x;
    int lane = tid & 63, wid = tid >> 6;
    int wm = (wid & 1) * 64, wn = (wid >> 1) * 64;
    int fr = lane & 15, fq = lane >> 4;
    int swz = (fq ^ ((fr >> 2) & 3)) * 16;    // lane-constant read swizzle (bytes)

    // staging: thread covers 16B chunks tid and tid+256 of each 8KB tile
    int r0 = tid >> 2,         c0 = (tid & 3) ^ ((r0 >> 2) & 3);
    int r1 = (tid + 256) >> 2, c1 = (tid & 3) ^ ((r1 >> 2) & 3);
    char* AsB = (char*)As;  char* BsB = (char*)Bs;
    void* dA0 = AsB + tid * 16;          void* dA1 = AsB + (tid + 256) * 16;
    void* dB0 = BsB + tid * 16;          void* dB1 = BsB + (tid + 256) * 16;

    int kend = KLIMIT ? min(K, m0 + 128) : K;

    f32x4 acc[4][4];
#pragma unroll
    for (int i = 0; i < 4; ++i)
#pragma unroll
    for (int j = 0; j < 4; ++j) acc[i][j] = f32x4{0.f, 0.f, 0.f, 0.f};

    for (int k0 = 0; k0 < kend; k0 += 32) {
        const unsigned short* Asrc = Ab;
        int koff = k0, ldax = lda;
        if (AMODE == 2 && k0 >= ksplit) { Asrc = A2; koff = k0 - ksplit; ldax = lda2; }

        gld_lds16(Asrc + (size_t)(m0 + r0) * ldax + koff + c0 * 8, dA0);
        gld_lds16(Asrc + (size_t)(m0 + r1) * ldax + koff + c1 * 8, dA1);
        gld_lds16(Bb   + (size_t)(n0 + r0) * ldb  + k0   + c0 * 8, dB0);
        gld_lds16(Bb   + (size_t)(n0 + r1) * ldb  + k0   + c1 * 8, dB1);
        __syncthreads();

        short8 a[4], b[4];
#pragma unroll
        for (int i = 0; i < 4; ++i) {
            a[i] = *(const short8*)(AsB + (wm + i * 16 + fr) * 64 + swz);
            b[i] = *(const short8*)(BsB + (wn + i * 16 + fr) * 64 + swz);
        }
#pragma unroll
        for (int i = 0; i < 4; ++i)
#pragma unroll
        for (int j = 0; j < 4; ++j)
            acc[i][j] = __builtin_amdgcn_mfma_f32_16x16x32_bf16(a[i], b[j], acc[i][j], 0, 0, 0);
        __syncthreads();
    }

    // epilogue: C/D layout col = lane&15, row = (lane>>4)*4 + reg [m89/m91]
#pragma unroll
    for (int i = 0; i < 4; ++i)
#pragma unroll
    for (int j = 0; j < 4; ++j)
#pragma unroll
    for (int r = 0; r < 4; ++r) {
        int row = m0 + wm + i * 16 + fq * 4 + r;
        int col = n0 + wn + j * 16 + fr;
        float v = acc[i][j][r];
        if (EPI == 0) {
            ((unsigned short*)C + (size_t)z * cStride)[(size_t)row * ldc + col] = f32_to_bf16(v);
        } else if (EPI == 2) {
            v += bias[col];
            v = v > 0.f ? v : 0.f;
            ((unsigned short*)C + (size_t)z * cStride)[(size_t)row * ldc + col] = f32_to_bf16(v);
        } else if (EPI == 3) {
            ((float*)C + (size_t)z * cStride)[(size_t)row * ldc + col] = v + bias[col];
        } else if (EPI == 4) {
            v *= bias[z * biasStride + row];
            ((unsigned short*)C + (size_t)z * cStride)[(size_t)row * ldc + col] = f32_to_bf16(v);
        } else {  // 5
            ((unsigned short*)C + (size_t)z * cStride)[(size_t)row * ldc + col] = f32_to_bf16(v * scale);
        }
    }
}

// ---------------------------------------------------------------------------
__global__ __launch_bounds__(256)
void f32_to_bf16_vec(const float* __restrict__ in, unsigned short* __restrict__ out)
{
    size_t i = ((size_t)blockIdx.x * 256 + threadIdx.x) * 8;
    *(short8*)(out + i) = load8_f32_as_bf16(in + i);
}

// fused Wq/Wk/Wv fp32 [1024,1024] -> bf16 transpose into WT (z selects source)
__global__ __launch_bounds__(256)
void transpose_qkv_w(const float* __restrict__ Wq, const float* __restrict__ Wk,
                     const float* __restrict__ Wv, unsigned short* __restrict__ WT)
{
    int z = blockIdx.z;
    const float* in = z == 0 ? Wq : (z == 1 ? Wk : Wv);
    unsigned short* out = WT + (size_t)z * 1024 * 1024;
    __shared__ float t[32][33];
    int tx = threadIdx.x, ty = threadIdx.y;
    int r0 = blockIdx.y * 32, c0 = blockIdx.x * 32;
    for (int i = ty; i < 32; i += 8)
        t[i][tx] = in[(size_t)(r0 + i) * 1024 + c0 + tx];
    __syncthreads();
    for (int i = ty; i < 32; i += 8)
        out[(size_t)(c0 + i) * 1024 + r0 + tx] = f32_to_bf16(t[tx][i]);
}

__global__ __launch_bounds__(256)
void transpose_f32_bf16(const float* __restrict__ in, unsigned short* __restrict__ out,
                        int rows, int cols)
{
    __shared__ float t[32][33];
    int tx = threadIdx.x, ty = threadIdx.y;
    int r0 = blockIdx.y * 32, c0 = blockIdx.x * 32;
    for (int i = ty; i < 32; i += 8)
        t[i][tx] = in[(size_t)(r0 + i) * cols + c0 + tx];
    __syncthreads();
    for (int i = ty; i < 32; i += 8)
        out[(size_t)(c0 + i) * rows + r0 + tx] = f32_to_bf16(t[tx][i]);
}

// v (bf16 inside qkv, ld 3072) -> vT [4][1024][2048]; 64x64 tiles, 128B lines
__global__ __launch_bounds__(256)
void transpose_v_kernel(const unsigned short* __restrict__ qkv, unsigned short* __restrict__ vT)
{
    int b = blockIdx.z;
    const unsigned short* in = qkv + (size_t)b * 2048 * 3072 + 2048;
    unsigned short* out = vT + (size_t)b * 1024 * 2048;
    __shared__ unsigned short t[64][65];
    int tx = threadIdx.x, ty = threadIdx.y;   // (64,4)
    int r0 = blockIdx.y * 64, c0 = blockIdx.x * 64;   // r over keys, c over dims
    for (int i = ty; i < 64; i += 4)
        t[i][tx] = in[(size_t)(r0 + i) * 3072 + c0 + tx];
    __syncthreads();
    for (int i = ty; i < 64; i += 4)
        out[(size_t)(c0 + i) * 2048 + r0 + tx] = t[tx][i];
}

// ---------------------------------------------------------------------------
// in-place causal softmax on bf16 S rows (2048 = 256 thr x short8), writes
// UNNORMALIZED exp(s-m) (zeros above diag) + invl[row]=1/sum for PV epilogue.
// ---------------------------------------------------------------------------
__global__ __launch_bounds__(256)
void softmax_causal_bf16(unsigned short* __restrict__ S, float* __restrict__ invl,
                         long sStride)
{
    int row = blockIdx.x, z = blockIdx.y;
    int tid = threadIdx.x;
    int lane = tid & 63, w = tid >> 6;
    int n = row + 1;
    unsigned short* prow = S + (size_t)z * sStride + (size_t)row * 2048;
    __shared__ float red[4];

    union { short8 s; unsigned short u[8]; } pk;
    pk.s = *(const short8*)(prow + tid * 8);
    float v[8];
#pragma unroll
    for (int t = 0; t < 8; ++t) v[t] = bf16_to_f32(pk.u[t]);

    int base = tid * 8;
    float m = -1e30f;
#pragma unroll
    for (int t = 0; t < 8; ++t) m = fmaxf(m, (base + t < n) ? v[t] : -1e30f);
#pragma unroll
    for (int o = 32; o > 0; o >>= 1) m = fmaxf(m, __shfl_down(m, o));
    if (lane == 0) red[w] = m;
    __syncthreads();
    m = fmaxf(fmaxf(red[0], red[1]), fmaxf(red[2], red[3]));
    __syncthreads();

    float s = 0.f;
    union { short8 s8; unsigned short u[8]; } outp;
#pragma unroll
    for (int t = 0; t < 8; ++t) {
        float e = (base + t < n) ? __expf(v[t] - m) : 0.f;
        s += e;
        outp.u[t] = f32_to_bf16(e);
    }
#pragma unroll
    for (int o = 32; o > 0; o >>= 1) s += __shfl_down(s, o);
    if (lane == 0) red[w] = s;
    __syncthreads();
    s = red[0] + red[1] + red[2] + red[3];
    if (tid == 0) invl[(size_t)z * 2048 + row] = 1.f / s;

    *(short8*)(prow + tid * 8) = outp.s8;
}

// ---------------------------------------------------------------------------
extern "C" void kernel_launch(void* const* d_in, const int* in_sizes, int n_in,
                              void* d_out, int out_size, void* d_ws, size_t ws_size,
                              hipStream_t stream)
{
    const float* x  = (const float*)d_in[0];   // [8192,1024]
    const float* Wq = (const float*)d_in[1];
    const float* Wk = (const float*)d_in[2];
    const float* Wv = (const float*)d_in[3];
    const float* W1 = (const float*)d_in[4];   // [2048,1024]
    const float* b1 = (const float*)d_in[5];
    const float* W2 = (const float*)d_in[6];   // [1024,1024]
    const float* b2 = (const float*)d_in[7];
    float* out = (float*)d_out;                // [8192,1024] fp32

    size_t off = 0;
    auto alloc = [&](size_t bytes) {
        char* r = (char*)d_ws + off;
        off += (bytes + 255) & ~(size_t)255;
        return r;
    };
    unsigned short* WT   = (unsigned short*)alloc((size_t)3072 * 1024 * 2);
    unsigned short* W1T  = (unsigned short*)alloc((size_t)1024 * 2048 * 2);
    unsigned short* W2T  = (unsigned short*)alloc((size_t)1024 * 1024 * 2);
    unsigned short* xb   = (unsigned short*)alloc((size_t)8192 * 1024 * 2);
    unsigned short* qkv  = (unsigned short*)alloc((size_t)8192 * 3072 * 2);
    unsigned short* vT   = (unsigned short*)alloc((size_t)4 * 1024 * 2048 * 2);
    unsigned short* attn = (unsigned short*)alloc((size_t)8192 * 1024 * 2);
    float*          invl = (float*)         alloc((size_t)4 * 2048 * 4);
    size_t fixed = off;

    // batched path: S bf16 [4,2048,2048] (in-place softmax -> P)
    size_t needBatched = fixed + (size_t)4 * 2048 * 2048 * 2 + 512;
    int NZ = (ws_size >= needBatched) ? 4 : 1;

    unsigned short* S  = (unsigned short*)alloc((size_t)NZ * 2048 * 2048 * 2);
    unsigned short* h1 = S;   // S dead after PV; MLP1 output aliases it

    dim3 tb(32, 8);
    transpose_qkv_w<<<dim3(32, 32, 3), tb, 0, stream>>>(Wq, Wk, Wv, WT);
    transpose_f32_bf16<<<dim3(32, 64), tb, 0, stream>>>(W1, W1T, 2048, 1024);
    transpose_f32_bf16<<<dim3(32, 32), tb, 0, stream>>>(W2, W2T, 1024, 1024);
    f32_to_bf16_vec<<<4096, 256, 0, stream>>>(x, xb);

    // QKV: qkv[8192,3072] = xb @ WT^T
    gemm128<0, 0, false, false><<<dim3(24, 64, 1), 256, 0, stream>>>(
        xb, nullptr, 1024, 0, 0, WT, 1024, qkv, 3072, 1024, 0, 0, 0, nullptr, 0, 0.f);

    transpose_v_kernel<<<dim3(16, 32, 4), dim3(64, 4), 0, stream>>>(qkv, vT);

    for (int b = 0; b < 4; b += NZ) {
        const unsigned short* qb = qkv + (size_t)b * 2048 * 3072;
        // S = bf16((q @ k^T) * 1/32), causal block skip
        gemm128<0, 5, true, false><<<dim3(16, 16, NZ), 256, 0, stream>>>(
            qb, nullptr, 3072, 0, 0, qb + 1024, 3072, S, 2048, 1024,
            (long)2048 * 3072, (long)2048 * 3072, (long)2048 * 2048, nullptr, 0, 0.03125f);
        // in-place softmax -> unnormalized exp + invl
        softmax_causal_bf16<<<dim3(2048, NZ), 256, 0, stream>>>(
            S, invl + (size_t)b * 2048, (long)2048 * 2048);
        // attn = (P @ v) * invl[row]   (K limited to diagonal block)
        gemm128<0, 4, false, true><<<dim3(8, 16, NZ), 256, 0, stream>>>(
            S, nullptr, 2048, 0, 0, vT + (size_t)b * 1024 * 2048, 2048,
            attn + (size_t)b * 2048 * 1024, 1024, 2048,
            (long)2048 * 2048, (long)1024 * 2048, (long)2048 * 1024,
            invl + (size_t)b * 2048, 2048, 0.f);
    }

    // MLP1: h1 = relu([attn | x] @ W1 + b1), split-A concat trick
    gemm128<2, 2, false, false><<<dim3(8, 64, 1), 256, 0, stream>>>(
        attn, xb, 1024, 1024, 1024, W1T, 2048, h1, 1024, 2048, 0, 0, 0, b1, 0, 0.f);
    // MLP2: out = h1 @ W2 + b2 (fp32 to d_out)
    gemm128<0, 3, false, false><<<dim3(8, 64, 1), 256, 0, stream>>>(
        h1, nullptr, 1024, 0, 0, W2T, 1024, out, 1024, 1024, 0, 0, 0, b2, 0, 0.f);
}

// Round 4
// 342.858 us; speedup vs baseline: 1.8173x; 1.1158x over previous
//
#include <hip/hip_runtime.h>
#include <stdint.h>

typedef __attribute__((ext_vector_type(8))) short short8;
typedef __attribute__((ext_vector_type(4))) float f32x4;

__device__ __forceinline__ unsigned short f32_to_bf16(float f) {
    unsigned int u = __float_as_uint(f);
    u += 0x7FFFu + ((u >> 16) & 1u);   // round-to-nearest-even
    return (unsigned short)(u >> 16);
}
__device__ __forceinline__ float bf16_to_f32(unsigned short h) {
    return __uint_as_float((unsigned int)h << 16);
}

__device__ __forceinline__ short8 load8_f32_as_bf16(const float* __restrict__ ap) {
    f32x4 f0 = *(const f32x4*)ap;
    f32x4 f1 = *(const f32x4*)(ap + 4);
    union { short8 s; unsigned short u[8]; } cv;
#pragma unroll
    for (int t = 0; t < 4; ++t) {
        cv.u[t]     = f32_to_bf16(f0[t]);
        cv.u[t + 4] = f32_to_bf16(f1[t]);
    }
    return cv.s;
}

// async global->LDS DMA, 16B/lane; LDS dest = wave-uniform base + lane*16 (m104/m108)
__device__ __forceinline__ void gld_lds16(const void* g, void* l) {
    __builtin_amdgcn_global_load_lds(
        (const __attribute__((address_space(1))) unsigned int*)(unsigned long long)(uintptr_t)g,
        (__attribute__((address_space(3))) unsigned int*)(unsigned int)(uintptr_t)l,
        16, 0, 0);
}

// ---------------------------------------------------------------------------
// NT GEMM: C[M,N] = A[M,K]*B[N,K]^T, bf16 in, fp32 accum.
// 128x128 tile, BK=64 (2 barriers per 64 k -- halves the barrier-drain tax vs
// BK=32), 4 waves 2x2, per iter: 8 DMA + 16 ds_read_b128 + 32 MFMA 16x16x32.
// LDS rows are 128B (== 32 dwords), so the row term drops out of the bank
// index; swizzle chunk' = c ^ (row&7) carries all entropy. Per 16-lane b128
// phase (fixed fq): chunk = (kh*4+fq)^(fr&7) spans all 8 values, 2 lanes each
// -> 2-deep/bank = conflict-free floor. SQ_LDS_BANK_CONFLICT ~= 4/b128 is
// structural (m134: 12 cyc vs 8 ideal), not a layout problem.
// AMODE: 0 = A only; 2 = split at ksplit: A then A2 (concat trick for MLP1).
// EPI: 0 bf16 | 2 relu(+bias[col]) bf16 | 3 +bias[col] fp32
//      4 *bias[z*biasStride+row] bf16 (PV invl) | 5 *scale bf16 (scores)
// CAUSAL: skip blocks n0 >= m0+128. KLIMIT: kend = min(K, m0+128).
// ---------------------------------------------------------------------------
template<int AMODE, int EPI, bool CAUSAL, bool KLIMIT>
__global__ __launch_bounds__(256, 4)
void gemm128(const unsigned short* __restrict__ A, const unsigned short* __restrict__ A2,
             int lda, int lda2, int ksplit,
             const unsigned short* __restrict__ B, int ldb,
             void* __restrict__ C, int ldc, int K,
             long aStride, long bStride, long cStride,
             const float* __restrict__ bias, long biasStride, float scale)
{
    int m0 = blockIdx.y * 128;
    int n0 = blockIdx.x * 128;
    if (CAUSAL && n0 >= m0 + 128) return;   // uniform early exit, before any barrier

    int z = blockIdx.z;
    const unsigned short* Ab = A + (size_t)z * aStride;
    const unsigned short* Bb = B + (size_t)z * bStride;

    __shared__ __align__(16) short As[128 * 64];   // 16 KB
    __shared__ __align__(16) short Bs[128 * 64];   // 16 KB

    int tid  = threadIdx.x;
    int lane = tid & 63, wid = tid >> 6;
    int wm = (wid & 1) * 64, wn = (wid >> 1) * 64;
    int fr = lane & 15, fq = lane >> 4;
    // fragment-read byte offsets within a 128B row (lane-constant):
    // global chunk g = kh*4+fq lives in slot g^(row&7); row&7 == fr&7 here
    int sw0 = ((fq    ) ^ (fr & 7)) * 16;
    int sw1 = ((fq ^ 4) ^ (fr & 7)) * 16;

    // DMA staging: thread covers rows rS + 32t (t=0..3) of each operand tile,
    // at swizzled source chunk cS; LDS dest is linear 16B/lane.
    int rS = tid >> 3;
    int cS = ((tid & 7) ^ (rS & 7)) * 8;   // element offset in k
    char* AsB = (char*)As; char* BsB = (char*)Bs;

    int kend = KLIMIT ? min(K, m0 + 128) : K;

    f32x4 acc[4][4];
#pragma unroll
    for (int i = 0; i < 4; ++i)
#pragma unroll
    for (int j = 0; j < 4; ++j) acc[i][j] = f32x4{0.f, 0.f, 0.f, 0.f};

    for (int k0 = 0; k0 < kend; k0 += 64) {
        const unsigned short* Asrc = Ab;
        int koff = k0, ldax = lda;
        if (AMODE == 2 && k0 >= ksplit) { Asrc = A2; koff = k0 - ksplit; ldax = lda2; }
        const unsigned short* pa = Asrc + (size_t)(m0 + rS) * ldax + koff + cS;
        const unsigned short* pb = Bb   + (size_t)(n0 + rS) * ldb  + k0   + cS;
#pragma unroll
        for (int t = 0; t < 4; ++t) {
            gld_lds16(pa + (size_t)(32 * t) * ldax, AsB + t * 4096 + tid * 16);
            gld_lds16(pb + (size_t)(32 * t) * ldb,  BsB + t * 4096 + tid * 16);
        }
        __syncthreads();

#pragma unroll
        for (int kh = 0; kh < 2; ++kh) {
            int sw = kh ? sw1 : sw0;
            short8 a[4], b[4];
#pragma unroll
            for (int i = 0; i < 4; ++i) {
                a[i] = *(const short8*)(AsB + (wm + i * 16 + fr) * 128 + sw);
                b[i] = *(const short8*)(BsB + (wn + i * 16 + fr) * 128 + sw);
            }
#pragma unroll
            for (int i = 0; i < 4; ++i)
#pragma unroll
            for (int j = 0; j < 4; ++j)
                acc[i][j] = __builtin_amdgcn_mfma_f32_16x16x32_bf16(a[i], b[j], acc[i][j], 0, 0, 0);
        }
        __syncthreads();
    }

    // epilogue: C/D layout col = lane&15, row = (lane>>4)*4 + reg [m89/m91]
#pragma unroll
    for (int i = 0; i < 4; ++i)
#pragma unroll
    for (int j = 0; j < 4; ++j)
#pragma unroll
    for (int r = 0; r < 4; ++r) {
        int row = m0 + wm + i * 16 + fq * 4 + r;
        int col = n0 + wn + j * 16 + fr;
        float v = acc[i][j][r];
        if (EPI == 0) {
            ((unsigned short*)C + (size_t)z * cStride)[(size_t)row * ldc + col] = f32_to_bf16(v);
        } else if (EPI == 2) {
            v += bias[col];
            v = v > 0.f ? v : 0.f;
            ((unsigned short*)C + (size_t)z * cStride)[(size_t)row * ldc + col] = f32_to_bf16(v);
        } else if (EPI == 3) {
            ((float*)C + (size_t)z * cStride)[(size_t)row * ldc + col] = v + bias[col];
        } else if (EPI == 4) {
            v *= bias[z * biasStride + row];
            ((unsigned short*)C + (size_t)z * cStride)[(size_t)row * ldc + col] = f32_to_bf16(v);
        } else {  // 5
            ((unsigned short*)C + (size_t)z * cStride)[(size_t)row * ldc + col] = f32_to_bf16(v * scale);
        }
    }
}

// ---------------------------------------------------------------------------
__global__ __launch_bounds__(256)
void f32_to_bf16_vec(const float* __restrict__ in, unsigned short* __restrict__ out)
{
    size_t i = ((size_t)blockIdx.x * 256 + threadIdx.x) * 8;
    *(short8*)(out + i) = load8_f32_as_bf16(in + i);
}

// fused Wq/Wk/Wv fp32 [1024,1024] -> bf16 transpose into WT (z selects source)
__global__ __launch_bounds__(256)
void transpose_qkv_w(const float* __restrict__ Wq, const float* __restrict__ Wk,
                     const float* __restrict__ Wv, unsigned short* __restrict__ WT)
{
    int z = blockIdx.z;
    const float* in = z == 0 ? Wq : (z == 1 ? Wk : Wv);
    unsigned short* out = WT + (size_t)z * 1024 * 1024;
    __shared__ float t[32][33];
    int tx = threadIdx.x, ty = threadIdx.y;
    int r0 = blockIdx.y * 32, c0 = blockIdx.x * 32;
    for (int i = ty; i < 32; i += 8)
        t[i][tx] = in[(size_t)(r0 + i) * 1024 + c0 + tx];
    __syncthreads();
    for (int i = ty; i < 32; i += 8)
        out[(size_t)(c0 + i) * 1024 + r0 + tx] = f32_to_bf16(t[tx][i]);
}

__global__ __launch_bounds__(256)
void transpose_f32_bf16(const float* __restrict__ in, unsigned short* __restrict__ out,
                        int rows, int cols)
{
    __shared__ float t[32][33];
    int tx = threadIdx.x, ty = threadIdx.y;
    int r0 = blockIdx.y * 32, c0 = blockIdx.x * 32;
    for (int i = ty; i < 32; i += 8)
        t[i][tx] = in[(size_t)(r0 + i) * cols + c0 + tx];
    __syncthreads();
    for (int i = ty; i < 32; i += 8)
        out[(size_t)(c0 + i) * rows + r0 + tx] = f32_to_bf16(t[tx][i]);
}

// v (bf16, [4][2048][1024]) -> vT [4][1024][2048]; 64x64 tiles
__global__ __launch_bounds__(256)
void transpose_v_kernel(const unsigned short* __restrict__ v, unsigned short* __restrict__ vT)
{
    int b = blockIdx.z;
    const unsigned short* in = v + (size_t)b * 2048 * 1024;
    unsigned short* out = vT + (size_t)b * 1024 * 2048;
    __shared__ unsigned short t[64][65];
    int tx = threadIdx.x, ty = threadIdx.y;   // (64,4)
    int r0 = blockIdx.y * 64, c0 = blockIdx.x * 64;   // r over keys, c over dims
    for (int i = ty; i < 64; i += 4)
        t[i][tx] = in[(size_t)(r0 + i) * 1024 + c0 + tx];
    __syncthreads();
    for (int i = ty; i < 64; i += 4)
        out[(size_t)(c0 + i) * 2048 + r0 + tx] = t[tx][i];
}

// ---------------------------------------------------------------------------
// in-place causal softmax on bf16 S rows (2048 = 256 thr x short8), writes
// UNNORMALIZED exp(s-m) (zeros above diag) + invl[row]=1/sum for PV epilogue.
// ---------------------------------------------------------------------------
__global__ __launch_bounds__(256)
void softmax_causal_bf16(unsigned short* __restrict__ S, float* __restrict__ invl,
                         long sStride)
{
    int row = blockIdx.x, z = blockIdx.y;
    int tid = threadIdx.x;
    int lane = tid & 63, w = tid >> 6;
    int n = row + 1;
    unsigned short* prow = S + (size_t)z * sStride + (size_t)row * 2048;
    __shared__ float red[4];

    union { short8 s; unsigned short u[8]; } pk;
    pk.s = *(const short8*)(prow + tid * 8);
    float v[8];
#pragma unroll
    for (int t = 0; t < 8; ++t) v[t] = bf16_to_f32(pk.u[t]);

    int base = tid * 8;
    float m = -1e30f;
#pragma unroll
    for (int t = 0; t < 8; ++t) m = fmaxf(m, (base + t < n) ? v[t] : -1e30f);
#pragma unroll
    for (int o = 32; o > 0; o >>= 1) m = fmaxf(m, __shfl_down(m, o));
    if (lane == 0) red[w] = m;
    __syncthreads();
    m = fmaxf(fmaxf(red[0], red[1]), fmaxf(red[2], red[3]));
    __syncthreads();

    float s = 0.f;
    union { short8 s8; unsigned short u[8]; } outp;
#pragma unroll
    for (int t = 0; t < 8; ++t) {
        float e = (base + t < n) ? __expf(v[t] - m) : 0.f;
        s += e;
        outp.u[t] = f32_to_bf16(e);
    }
#pragma unroll
    for (int o = 32; o > 0; o >>= 1) s += __shfl_down(s, o);
    if (lane == 0) red[w] = s;
    __syncthreads();
    s = red[0] + red[1] + red[2] + red[3];
    if (tid == 0) invl[(size_t)z * 2048 + row] = 1.f / s;

    *(short8*)(prow + tid * 8) = outp.s8;
}

// ---------------------------------------------------------------------------
extern "C" void kernel_launch(void* const* d_in, const int* in_sizes, int n_in,
                              void* d_out, int out_size, void* d_ws, size_t ws_size,
                              hipStream_t stream)
{
    const float* x  = (const float*)d_in[0];   // [8192,1024]
    const float* Wq = (const float*)d_in[1];
    const float* Wk = (const float*)d_in[2];
    const float* Wv = (const float*)d_in[3];
    const float* W1 = (const float*)d_in[4];   // [2048,1024]
    const float* b1 = (const float*)d_in[5];
    const float* W2 = (const float*)d_in[6];   // [1024,1024]
    const float* b2 = (const float*)d_in[7];
    float* out = (float*)d_out;                // [8192,1024] fp32

    size_t off = 0;
    auto alloc = [&](size_t bytes) {
        char* r = (char*)d_ws + off;
        off += (bytes + 255) & ~(size_t)255;
        return r;
    };
    const size_t TOK = (size_t)8192 * 1024;    // tokens x dim
    unsigned short* WT   = (unsigned short*)alloc((size_t)3072 * 1024 * 2);
    unsigned short* W1T  = (unsigned short*)alloc((size_t)1024 * 2048 * 2);
    unsigned short* W2T  = (unsigned short*)alloc((size_t)1024 * 1024 * 2);
    unsigned short* xb   = (unsigned short*)alloc(TOK * 2);
    unsigned short* vT   = (unsigned short*)alloc((size_t)4 * 1024 * 2048 * 2);
    unsigned short* attn = (unsigned short*)alloc(TOK * 2);
    float*          invl = (float*)         alloc((size_t)4 * 2048 * 4);
    // q|k|v contiguous; v dead after vT build, S (33.5MB) aliases it.
    unsigned short* q    = (unsigned short*)alloc(TOK * 2 * 2 + (size_t)4 * 2048 * 2048 * 2);
    unsigned short* k    = q + TOK;
    unsigned short* v    = k + TOK;
    unsigned short* S    = v;                  // [4][2048][2048] bf16, aliases v
    unsigned short* h1   = S;                  // S dead after PV; MLP1 out aliases it
    // peak ws use: ~130.1 MB (< the 138.4 MB footprint R0 ran with)

    dim3 tb(32, 8);
    transpose_qkv_w<<<dim3(32, 32, 3), tb, 0, stream>>>(Wq, Wk, Wv, WT);
    transpose_f32_bf16<<<dim3(32, 64), tb, 0, stream>>>(W1, W1T, 2048, 1024);
    transpose_f32_bf16<<<dim3(32, 32), tb, 0, stream>>>(W2, W2T, 1024, 1024);
    f32_to_bf16_vec<<<4096, 256, 0, stream>>>(x, xb);

    // QKV (one launch, z = {q,k,v}): [8192,1024] = xb @ (WT+z*1M)^T
    gemm128<0, 0, false, false><<<dim3(8, 64, 3), 256, 0, stream>>>(
        xb, nullptr, 1024, 0, 0, WT, 1024, q, 1024, 1024,
        0, (long)1024 * 1024, (long)TOK, nullptr, 0, 0.f);

    transpose_v_kernel<<<dim3(16, 32, 4), dim3(64, 4), 0, stream>>>(v, vT);

    // S = bf16((q @ k^T) / 32), causal block skip, all 4 batches
    gemm128<0, 5, true, false><<<dim3(16, 16, 4), 256, 0, stream>>>(
        q, nullptr, 1024, 0, 0, k, 1024, S, 2048, 1024,
        (long)2048 * 1024, (long)2048 * 1024, (long)2048 * 2048, nullptr, 0, 0.03125f);
    // in-place softmax -> unnormalized exp + invl
    softmax_causal_bf16<<<dim3(2048, 4), 256, 0, stream>>>(S, invl, (long)2048 * 2048);
    // attn = (P @ v) * invl[row]  (K limited to diagonal block)
    gemm128<0, 4, false, true><<<dim3(8, 16, 4), 256, 0, stream>>>(
        S, nullptr, 2048, 0, 0, vT, 2048, attn, 1024, 2048,
        (long)2048 * 2048, (long)1024 * 2048, (long)2048 * 1024, invl, 2048, 0.f);

    // MLP1: h1 = relu([attn | x] @ W1 + b1), split-A concat trick
    gemm128<2, 2, false, false><<<dim3(8, 64, 1), 256, 0, stream>>>(
        attn, xb, 1024, 1024, 1024, W1T, 2048, h1, 1024, 2048, 0, 0, 0, b1, 0, 0.f);
    // MLP2: out = h1 @ W2 + b2 (fp32 to d_out)
    gemm128<0, 3, false, false><<<dim3(8, 64, 1), 256, 0, stream>>>(
        h1, nullptr, 1024, 0, 0, W2T, 1024, out, 1024, 1024, 0, 0, 0, b2, 0, 0.f);
}

// Round 5
// 325.199 us; speedup vs baseline: 1.9160x; 1.0543x over previous
//
#include <hip/hip_runtime.h>
#include <stdint.h>

typedef __attribute__((ext_vector_type(8))) short short8;
typedef __attribute__((ext_vector_type(4))) float f32x4;

__device__ __forceinline__ unsigned short f32_to_bf16(float f) {
    unsigned int u = __float_as_uint(f);
    u += 0x7FFFu + ((u >> 16) & 1u);   // round-to-nearest-even
    return (unsigned short)(u >> 16);
}
__device__ __forceinline__ float bf16_to_f32(unsigned short h) {
    return __uint_as_float((unsigned int)h << 16);
}

__device__ __forceinline__ short8 load8_f32_as_bf16(const float* __restrict__ ap) {
    f32x4 f0 = *(const f32x4*)ap;
    f32x4 f1 = *(const f32x4*)(ap + 4);
    union { short8 s; unsigned short u[8]; } cv;
#pragma unroll
    for (int t = 0; t < 4; ++t) {
        cv.u[t]     = f32_to_bf16(f0[t]);
        cv.u[t + 4] = f32_to_bf16(f1[t]);
    }
    return cv.s;
}

// async global->LDS DMA, 16B/lane; LDS dest = wave-uniform base + lane*16 (m104/m108)
__device__ __forceinline__ void gld_lds16(const void* g, void* l) {
    __builtin_amdgcn_global_load_lds(
        (const __attribute__((address_space(1))) unsigned int*)(unsigned long long)(uintptr_t)g,
        (__attribute__((address_space(3))) unsigned int*)(unsigned int)(uintptr_t)l,
        16, 0, 0);
}

// ---------------------------------------------------------------------------
// NT GEMM: C[M,N] = A[M,K]*B[N,K]^T, bf16 in, fp32 accum.
// 128x128 tile, BK=64, 4 waves 2x2, per iter: 8 DMA + 16 ds_read_b128 + 32 MFMA.
// LDS swizzle chunk' = c ^ (row&7): SQ_LDS_BANK_CONFLICT == 0 measured (R3).
// XCD swizzle: workgroups go round-robin to 8 XCDs (lin&7 ~ XCC_ID, m09).
// Remap so XCD x owns m-chunk [x*mb/8,(x+1)*mb/8), m fast / n slow: each
// A-strip is fetched by exactly one XCD; B-strip once per XCD sweep. R3's
// QKV FETCH was 178 MB vs 56 MB unique -- cross-XCD re-fetch, this kills it.
// AMODE: 0 = A only; 2 = split at ksplit: A then A2 (concat trick for MLP1).
// EPI: 0 bf16 | 2 relu(+bias[col]) bf16 | 3 +bias[col] fp32
//      4 *bias[z*biasStride+row] bf16 (PV invl) | 5 *scale bf16 (scores)
// CAUSAL: skip blocks n0 >= m0+128. KLIMIT: kend = min(K, m0+128).
// ---------------------------------------------------------------------------
template<int AMODE, int EPI, bool CAUSAL, bool KLIMIT>
__global__ __launch_bounds__(256, 4)
void gemm128(const unsigned short* __restrict__ A, const unsigned short* __restrict__ A2,
             int lda, int lda2, int ksplit,
             const unsigned short* __restrict__ B, int ldb,
             void* __restrict__ C, int ldc, int K,
             long aStride, long bStride, long cStride,
             const float* __restrict__ bias, long biasStride, float scale)
{
    // XCD-aware remap (gridDim.y % 8 == 0 for all call sites; gx*gy % 8 == 0
    // keeps the lin&7 phase consistent across blockIdx.z)
    int mblk = blockIdx.y, nblk = blockIdx.x;
    if ((gridDim.y & 7) == 0) {
        int lin = blockIdx.y * gridDim.x + blockIdx.x;
        int mchunk = gridDim.y >> 3;
        int xcd = lin & 7, idx = lin >> 3;
        mblk = xcd * mchunk + idx % mchunk;   // m fast within XCD's chunk
        nblk = idx / mchunk;                  // n slow
    }
    int m0 = mblk * 128;
    int n0 = nblk * 128;
    if (CAUSAL && n0 >= m0 + 128) return;   // uniform early exit, before any barrier

    int z = blockIdx.z;
    const unsigned short* Ab = A + (size_t)z * aStride;
    const unsigned short* Bb = B + (size_t)z * bStride;

    __shared__ __align__(16) short As[128 * 64];   // 16 KB
    __shared__ __align__(16) short Bs[128 * 64];   // 16 KB

    int tid  = threadIdx.x;
    int lane = tid & 63, wid = tid >> 6;
    int wm = (wid & 1) * 64, wn = (wid >> 1) * 64;
    int fr = lane & 15, fq = lane >> 4;
    // fragment-read byte offsets within a 128B row (lane-constant):
    // global chunk g = kh*4+fq lives in slot g^(row&7); row&7 == fr&7 here
    int sw0 = ((fq    ) ^ (fr & 7)) * 16;
    int sw1 = ((fq ^ 4) ^ (fr & 7)) * 16;

    // DMA staging: thread covers rows rS + 32t (t=0..3), swizzled source chunk
    int rS = tid >> 3;
    int cS = ((tid & 7) ^ (rS & 7)) * 8;   // element offset in k
    char* AsB = (char*)As; char* BsB = (char*)Bs;

    int kend = KLIMIT ? min(K, m0 + 128) : K;

    f32x4 acc[4][4];
#pragma unroll
    for (int i = 0; i < 4; ++i)
#pragma unroll
    for (int j = 0; j < 4; ++j) acc[i][j] = f32x4{0.f, 0.f, 0.f, 0.f};

    for (int k0 = 0; k0 < kend; k0 += 64) {
        const unsigned short* Asrc = Ab;
        int koff = k0, ldax = lda;
        if (AMODE == 2 && k0 >= ksplit) { Asrc = A2; koff = k0 - ksplit; ldax = lda2; }
        const unsigned short* pa = Asrc + (size_t)(m0 + rS) * ldax + koff + cS;
        const unsigned short* pb = Bb   + (size_t)(n0 + rS) * ldb  + k0   + cS;
#pragma unroll
        for (int t = 0; t < 4; ++t) {
            gld_lds16(pa + (size_t)(32 * t) * ldax, AsB + t * 4096 + tid * 16);
            gld_lds16(pb + (size_t)(32 * t) * ldb,  BsB + t * 4096 + tid * 16);
        }
        __syncthreads();

#pragma unroll
        for (int kh = 0; kh < 2; ++kh) {
            int sw = kh ? sw1 : sw0;
            short8 a[4], b[4];
#pragma unroll
            for (int i = 0; i < 4; ++i) {
                a[i] = *(const short8*)(AsB + (wm + i * 16 + fr) * 128 + sw);
                b[i] = *(const short8*)(BsB + (wn + i * 16 + fr) * 128 + sw);
            }
#pragma unroll
            for (int i = 0; i < 4; ++i)
#pragma unroll
            for (int j = 0; j < 4; ++j)
                acc[i][j] = __builtin_amdgcn_mfma_f32_16x16x32_bf16(a[i], b[j], acc[i][j], 0, 0, 0);
        }
        __syncthreads();
    }

    // epilogue: C/D layout col = lane&15, row = (lane>>4)*4 + reg [m89/m91]
#pragma unroll
    for (int i = 0; i < 4; ++i)
#pragma unroll
    for (int j = 0; j < 4; ++j)
#pragma unroll
    for (int r = 0; r < 4; ++r) {
        int row = m0 + wm + i * 16 + fq * 4 + r;
        int col = n0 + wn + j * 16 + fr;
        float v = acc[i][j][r];
        if (EPI == 0) {
            ((unsigned short*)C + (size_t)z * cStride)[(size_t)row * ldc + col] = f32_to_bf16(v);
        } else if (EPI == 2) {
            v += bias[col];
            v = v > 0.f ? v : 0.f;
            ((unsigned short*)C + (size_t)z * cStride)[(size_t)row * ldc + col] = f32_to_bf16(v);
        } else if (EPI == 3) {
            ((float*)C + (size_t)z * cStride)[(size_t)row * ldc + col] = v + bias[col];
        } else if (EPI == 4) {
            v *= bias[z * biasStride + row];
            ((unsigned short*)C + (size_t)z * cStride)[(size_t)row * ldc + col] = f32_to_bf16(v);
        } else {  // 5
            ((unsigned short*)C + (size_t)z * cStride)[(size_t)row * ldc + col] = f32_to_bf16(v * scale);
        }
    }
}

// ---------------------------------------------------------------------------
__global__ __launch_bounds__(256)
void f32_to_bf16_vec(const float* __restrict__ in, unsigned short* __restrict__ out)
{
    size_t i = ((size_t)blockIdx.x * 256 + threadIdx.x) * 8;
    *(short8*)(out + i) = load8_f32_as_bf16(in + i);
}

// fused Wq/Wk/Wv fp32 [1024,1024] -> bf16 transpose into WT (z selects source)
__global__ __launch_bounds__(256)
void transpose_qkv_w(const float* __restrict__ Wq, const float* __restrict__ Wk,
                     const float* __restrict__ Wv, unsigned short* __restrict__ WT)
{
    int z = blockIdx.z;
    const float* in = z == 0 ? Wq : (z == 1 ? Wk : Wv);
    unsigned short* out = WT + (size_t)z * 1024 * 1024;
    __shared__ float t[32][33];
    int tx = threadIdx.x, ty = threadIdx.y;
    int r0 = blockIdx.y * 32, c0 = blockIdx.x * 32;
    for (int i = ty; i < 32; i += 8)
        t[i][tx] = in[(size_t)(r0 + i) * 1024 + c0 + tx];
    __syncthreads();
    for (int i = ty; i < 32; i += 8)
        out[(size_t)(c0 + i) * 1024 + r0 + tx] = f32_to_bf16(t[tx][i]);
}

__global__ __launch_bounds__(256)
void transpose_f32_bf16(const float* __restrict__ in, unsigned short* __restrict__ out,
                        int rows, int cols)
{
    __shared__ float t[32][33];
    int tx = threadIdx.x, ty = threadIdx.y;
    int r0 = blockIdx.y * 32, c0 = blockIdx.x * 32;
    for (int i = ty; i < 32; i += 8)
        t[i][tx] = in[(size_t)(r0 + i) * cols + c0 + tx];
    __syncthreads();
    for (int i = ty; i < 32; i += 8)
        out[(size_t)(c0 + i) * rows + r0 + tx] = f32_to_bf16(t[tx][i]);
}

// v (bf16, [4][2048][1024]) -> vT [4][1024][2048]; 64x64 tiles
__global__ __launch_bounds__(256)
void transpose_v_kernel(const unsigned short* __restrict__ v, unsigned short* __restrict__ vT)
{
    int b = blockIdx.z;
    const unsigned short* in = v + (size_t)b * 2048 * 1024;
    unsigned short* out = vT + (size_t)b * 1024 * 2048;
    __shared__ unsigned short t[64][65];
    int tx = threadIdx.x, ty = threadIdx.y;   // (64,4)
    int r0 = blockIdx.y * 64, c0 = blockIdx.x * 64;   // r over keys, c over dims
    for (int i = ty; i < 64; i += 4)
        t[i][tx] = in[(size_t)(r0 + i) * 1024 + c0 + tx];
    __syncthreads();
    for (int i = ty; i < 64; i += 4)
        out[(size_t)(c0 + i) * 2048 + r0 + tx] = t[tx][i];
}

// ---------------------------------------------------------------------------
// in-place causal softmax on bf16 S rows, TRIANGULAR: only k < nlim =
// (row & ~127)+128 is read/written -- PV's KLIMIT (kend = m0+128 >= nlim for
// every row in the block) never reads past it, and the causal scores GEMM
// wrote exactly cols < nlim (poison-safe). Writes UNNORMALIZED exp(s-m)
// (zeros in [n, nlim)) + invl[row] = 1/sum for the PV epilogue.
// ---------------------------------------------------------------------------
__global__ __launch_bounds__(256)
void softmax_causal_bf16(unsigned short* __restrict__ S, float* __restrict__ invl,
                         long sStride)
{
    int row = blockIdx.x, z = blockIdx.y;
    int tid = threadIdx.x;
    int lane = tid & 63, w = tid >> 6;
    int n = row + 1;
    int nlim = (row & ~127) + 128;
    unsigned short* prow = S + (size_t)z * sStride + (size_t)row * 2048;
    __shared__ float red[4];

    int base = tid * 8;
    bool act = base < nlim;

    union { short8 s; unsigned short u[8]; } pk;
    float v[8];
    if (act) {
        pk.s = *(const short8*)(prow + base);
#pragma unroll
        for (int t = 0; t < 8; ++t) v[t] = bf16_to_f32(pk.u[t]);
    }

    float m = -1e30f;
    if (act) {
#pragma unroll
        for (int t = 0; t < 8; ++t) m = fmaxf(m, (base + t < n) ? v[t] : -1e30f);
    }
#pragma unroll
    for (int o = 32; o > 0; o >>= 1) m = fmaxf(m, __shfl_down(m, o));
    if (lane == 0) red[w] = m;
    __syncthreads();
    m = fmaxf(fmaxf(red[0], red[1]), fmaxf(red[2], red[3]));
    __syncthreads();

    float s = 0.f;
    union { short8 s8; unsigned short u[8]; } outp;
    if (act) {
#pragma unroll
        for (int t = 0; t < 8; ++t) {
            float e = (base + t < n) ? __expf(v[t] - m) : 0.f;
            s += e;
            outp.u[t] = f32_to_bf16(e);
        }
    }
#pragma unroll
    for (int o = 32; o > 0; o >>= 1) s += __shfl_down(s, o);
    if (lane == 0) red[w] = s;
    __syncthreads();
    s = red[0] + red[1] + red[2] + red[3];
    if (tid == 0) invl[(size_t)z * 2048 + row] = 1.f / s;

    if (act) *(short8*)(prow + base) = outp.s8;
}

// ---------------------------------------------------------------------------
extern "C" void kernel_launch(void* const* d_in, const int* in_sizes, int n_in,
                              void* d_out, int out_size, void* d_ws, size_t ws_size,
                              hipStream_t stream)
{
    const float* x  = (const float*)d_in[0];   // [8192,1024]
    const float* Wq = (const float*)d_in[1];
    const float* Wk = (const float*)d_in[2];
    const float* Wv = (const float*)d_in[3];
    const float* W1 = (const float*)d_in[4];   // [2048,1024]
    const float* b1 = (const float*)d_in[5];
    const float* W2 = (const float*)d_in[6];   // [1024,1024]
    const float* b2 = (const float*)d_in[7];
    float* out = (float*)d_out;                // [8192,1024] fp32

    size_t off = 0;
    auto alloc = [&](size_t bytes) {
        char* r = (char*)d_ws + off;
        off += (bytes + 255) & ~(size_t)255;
        return r;
    };
    const size_t TOK = (size_t)8192 * 1024;    // tokens x dim
    unsigned short* WT   = (unsigned short*)alloc((size_t)3072 * 1024 * 2);
    unsigned short* W1T  = (unsigned short*)alloc((size_t)1024 * 2048 * 2);
    unsigned short* W2T  = (unsigned short*)alloc((size_t)1024 * 1024 * 2);
    unsigned short* xb   = (unsigned short*)alloc(TOK * 2);
    unsigned short* vT   = (unsigned short*)alloc((size_t)4 * 1024 * 2048 * 2);
    unsigned short* attn = (unsigned short*)alloc(TOK * 2);
    float*          invl = (float*)         alloc((size_t)4 * 2048 * 4);
    // q|k|v contiguous; v dead after vT build, S (33.5MB) aliases it.
    unsigned short* q    = (unsigned short*)alloc(TOK * 2 * 2 + (size_t)4 * 2048 * 2048 * 2);
    unsigned short* k    = q + TOK;
    unsigned short* v    = k + TOK;
    unsigned short* S    = v;                  // [4][2048][2048] bf16, aliases v
    unsigned short* h1   = S;                  // S dead after PV; MLP1 out aliases it
    // peak ws use: ~130.1 MB

    dim3 tb(32, 8);
    transpose_qkv_w<<<dim3(32, 32, 3), tb, 0, stream>>>(Wq, Wk, Wv, WT);
    transpose_f32_bf16<<<dim3(32, 64), tb, 0, stream>>>(W1, W1T, 2048, 1024);
    transpose_f32_bf16<<<dim3(32, 32), tb, 0, stream>>>(W2, W2T, 1024, 1024);
    f32_to_bf16_vec<<<4096, 256, 0, stream>>>(x, xb);

    // QKV (one launch, z = {q,k,v}): [8192,1024] = xb @ (WT+z*1M)^T
    gemm128<0, 0, false, false><<<dim3(8, 64, 3), 256, 0, stream>>>(
        xb, nullptr, 1024, 0, 0, WT, 1024, q, 1024, 1024,
        0, (long)1024 * 1024, (long)TOK, nullptr, 0, 0.f);

    transpose_v_kernel<<<dim3(16, 32, 4), dim3(64, 4), 0, stream>>>(v, vT);

    // S = bf16((q @ k^T) / 32), causal block skip, all 4 batches
    gemm128<0, 5, true, false><<<dim3(16, 16, 4), 256, 0, stream>>>(
        q, nullptr, 1024, 0, 0, k, 1024, S, 2048, 1024,
        (long)2048 * 1024, (long)2048 * 1024, (long)2048 * 2048, nullptr, 0, 0.03125f);
    // in-place triangular softmax -> unnormalized exp + invl
    softmax_causal_bf16<<<dim3(2048, 4), 256, 0, stream>>>(S, invl, (long)2048 * 2048);
    // attn = (P @ v) * invl[row]  (K limited to diagonal block)
    gemm128<0, 4, false, true><<<dim3(8, 16, 4), 256, 0, stream>>>(
        S, nullptr, 2048, 0, 0, vT, 2048, attn, 1024, 2048,
        (long)2048 * 2048, (long)1024 * 2048, (long)2048 * 1024, invl, 2048, 0.f);

    // MLP1: h1 = relu([attn | x] @ W1 + b1), split-A concat trick
    gemm128<2, 2, false, false><<<dim3(8, 64, 1), 256, 0, stream>>>(
        attn, xb, 1024, 1024, 1024, W1T, 2048, h1, 1024, 2048, 0, 0, 0, b1, 0, 0.f);
    // MLP2: out = h1 @ W2 + b2 (fp32 to d_out)
    gemm128<0, 3, false, false><<<dim3(8, 64, 1), 256, 0, stream>>>(
        h1, nullptr, 1024, 0, 0, W2T, 1024, out, 1024, 1024, 0, 0, 0, b2, 0, 0.f);
}